// Round 13
// baseline (226.645 us; speedup 1.0000x reference)
//
#include <hip/hip_runtime.h>
#include <math.h>

#define NATOMS   1025
#define GSTRIDE  1040               // padded row stride in Gp (floats)
#define GELEMS   (1025*GSTRIDE)
#define RSTRIDE  1026               // rowsLds stride (even -> float2 aligned)
#define NNZ      32
#define NBATCH   64
#define REGL     0.0067153485f      // softplus(-5) in fp32

// DPP cross-lane helpers (VALU-latency, no LDS). old=0, bound_ctrl=false ->
// shifted-in lanes contribute (0, idx 0): harmless for abs-max / sum.
#define DPPF(x, ctrl) __int_as_float(__builtin_amdgcn_update_dpp(0, __float_as_int(x), (ctrl), 0xF, 0xF, false))

__device__ __forceinline__ float wave_sum64(float x) {
    x += DPPF(x, 0x111);
    x += DPPF(x, 0x112);
    x += DPPF(x, 0x114);
    x += DPPF(x, 0x118);
    x += DPPF(x, 0x142);
    x += DPPF(x, 0x143);
    return __int_as_float(__builtin_amdgcn_readlane(__float_as_int(x), 63));
}
__device__ __forceinline__ float readlane_f(float x, int l) {
    return __int_as_float(__builtin_amdgcn_readlane(__float_as_int(x), l));
}
// (max, lowest-index) argmax across the wave, same data movement as wave_sum64
__device__ __forceinline__ void wave_argmax64(float& v, int& idx) {
#define AM_STEP(ctrl) {                                                        \
        float ov = DPPF(v, ctrl);                                              \
        int   oi = __builtin_amdgcn_update_dpp(0, idx, (ctrl), 0xF, 0xF, false);\
        if (ov > v || (ov == v && oi < idx)) { v = ov; idx = oi; } }
    AM_STEP(0x111) AM_STEP(0x112) AM_STEP(0x114) AM_STEP(0x118)
    AM_STEP(0x142) AM_STEP(0x143)
#undef AM_STEP
    v   = readlane_f(v, 63);
    idx = __builtin_amdgcn_readlane(idx, 63);
}

// ---------------------------------------------------------------------------
// fused gram+projy. blockIdx.z < nsplit: gram (triangular bx<=by, 128x128 tile,
// 8x8/thread, split-K partial). Each partial is written FULLY SYMMETRIC:
// upper tile normally + mirrored tile via register float4 stores (bx!=by).
// blockIdx.z == nsplit: projy (64-atom x 16-batch tile).
// ---------------------------------------------------------------------------
__global__ __launch_bounds__(256)
void gramprojy_kernel(const float* __restrict__ X0, const float* __restrict__ y,
                      float* __restrict__ Gout, float* __restrict__ PY,
                      int kLen, int nsplit) {
    __shared__ float lds[8192];
    const int tid = threadIdx.x;

    if ((int)blockIdx.z < nsplit) {
        // ================= gram role =================
        const int bx = blockIdx.x, by = blockIdx.y, bz = blockIdx.z;
        if (by < bx) return;
        float* As = lds;            // [32][128]
        float* Bs = lds + 4096;     // [32][128]
        const int a0 = bx * 128, b0 = by * 128;
        float* __restrict__ Gp = Gout + (size_t)bz * GELEMS;
        const int tx = tid & 15;
        const int ty = tid >> 4;
        const int lr = tid >> 5;
        const int lc = (tid & 31) * 4;
        const bool aIn = (a0 + 128) <= 1024;
        const bool bIn = (b0 + 128) <= 1024;

        float acc[8][8];
#pragma unroll
        for (int m = 0; m < 8; ++m)
#pragma unroll
            for (int n = 0; n < 8; ++n) acc[m][n] = 0.0f;

        const int kBase = bz * kLen;
        for (int kc = 0; kc < kLen; kc += 32) {
#pragma unroll
            for (int rr = 0; rr < 4; ++rr) {
                const int r = lr + rr * 8;
                const int l = kBase + kc + r;
                if (aIn) {
                    *(float4*)&As[r * 128 + lc] = *(const float4*)&X0[(size_t)l * 1024 + a0 + lc];
                } else {
#pragma unroll
                    for (int k = 0; k < 4; ++k) {
                        const int col = a0 + lc + k;
                        As[r * 128 + lc + k] = (col < 1024) ? X0[(size_t)l * 1024 + col]
                                                            : (col == 1024 ? 1.0f : 0.0f);
                    }
                }
                if (bIn) {
                    *(float4*)&Bs[r * 128 + lc] = *(const float4*)&X0[(size_t)l * 1024 + b0 + lc];
                } else {
#pragma unroll
                    for (int k = 0; k < 4; ++k) {
                        const int col = b0 + lc + k;
                        Bs[r * 128 + lc + k] = (col < 1024) ? X0[(size_t)l * 1024 + col]
                                                            : (col == 1024 ? 1.0f : 0.0f);
                    }
                }
            }
            __syncthreads();
#pragma unroll 8
            for (int l = 0; l < 32; ++l) {
                float4 a01 = *(const float4*)&As[l * 128 + ty * 8];
                float4 a23 = *(const float4*)&As[l * 128 + ty * 8 + 4];
                float4 bA  = *(const float4*)&Bs[l * 128 + tx * 4];
                float4 bB  = *(const float4*)&Bs[l * 128 + 64 + tx * 4];
                float am[8] = {a01.x, a01.y, a01.z, a01.w, a23.x, a23.y, a23.z, a23.w};
                float bn[8] = {bA.x, bA.y, bA.z, bA.w, bB.x, bB.y, bB.z, bB.w};
#pragma unroll
                for (int m = 0; m < 8; ++m)
#pragma unroll
                    for (int n = 0; n < 8; ++n)
                        acc[m][n] += am[m] * bn[n];
            }
            __syncthreads();
        }

        // upper tile write (rows a, cols b)
#pragma unroll
        for (int m = 0; m < 8; ++m) {
            const int a = a0 + ty * 8 + m;
            if (a >= NATOMS) continue;
            const int bAc = b0 + tx * 4;
            const int bBc = b0 + 64 + tx * 4;
            if (bAc < GSTRIDE) {
                *(float4*)&Gp[(size_t)a * GSTRIDE + bAc] =
                    make_float4(acc[m][0], acc[m][1], acc[m][2], acc[m][3]);
            }
            if (bBc < GSTRIDE) {
                *(float4*)&Gp[(size_t)a * GSTRIDE + bBc] =
                    make_float4(acc[m][4], acc[m][5], acc[m][6], acc[m][7]);
            }
        }
        // mirror write (rows b, cols a), register float4s; bx<by => a-range <1024
        if (bx != by) {
#pragma unroll
            for (int n = 0; n < 8; ++n) {
                const int colg = b0 + ((n < 4) ? (tx * 4 + n) : (64 + tx * 4 + (n - 4)));
                if (colg >= NATOMS) continue;
                const int a = a0 + ty * 8;
                *(float4*)&Gp[(size_t)colg * GSTRIDE + a] =
                    make_float4(acc[0][n], acc[1][n], acc[2][n], acc[3][n]);
                *(float4*)&Gp[(size_t)colg * GSTRIDE + a + 4] =
                    make_float4(acc[4][n], acc[5][n], acc[6][n], acc[7][n]);
            }
        }
    } else {
        // ================= projy role =================
        const int pw = blockIdx.y * 9 + blockIdx.x;
        if (pw >= 68) return;
        const int a0 = (pw % 17) * 64;
        const int b0 = (pw / 17) * 16;
        float* Ds = lds;            // [32][64]
        float* Ys = lds + 2048;     // [32][17]
        const int tx = tid & 15;
        const int ty = tid >> 4;
        const bool aIn = (a0 + 64) <= 1024;

        float acc[4] = {0.0f, 0.0f, 0.0f, 0.0f};

        for (int kc = 0; kc < 1024; kc += 32) {
            {
                const int r  = tid >> 4;
                const int c4 = (tid & 15) * 4;
#pragma unroll
                for (int rr = 0; rr < 2; ++rr) {
                    const int row = r + rr * 16;
                    const int l = kc + row;
                    if (aIn) {
                        *(float4*)&Ds[row * 64 + c4] = *(const float4*)&X0[(size_t)l * 1024 + a0 + c4];
                    } else {
#pragma unroll
                        for (int k = 0; k < 4; ++k) {
                            const int col = a0 + c4 + k;
                            Ds[row * 64 + c4 + k] = (col < 1024) ? X0[(size_t)l * 1024 + col]
                                                                 : (col == 1024 ? 1.0f : 0.0f);
                        }
                    }
                }
            }
            for (int e = tid; e < 512; e += 256) {
                const int l = e & 31, bb = e >> 5;
                Ys[l * 17 + bb] = y[(size_t)(b0 + bb) * 1024 + kc + l];
            }
            __syncthreads();
#pragma unroll 8
            for (int l = 0; l < 32; ++l) {
                const float yv = Ys[l * 17 + ty];
                float4 dv = *(const float4*)&Ds[l * 64 + tx * 4];
                acc[0] += yv * dv.x; acc[1] += yv * dv.y;
                acc[2] += yv * dv.z; acc[3] += yv * dv.w;
            }
            __syncthreads();
        }
        const int a = a0 + tx * 4;
        if (a < GSTRIDE) {
            *(float4*)&PY[(size_t)(b0 + ty) * GSTRIDE + a] =
                make_float4(acc[0], acc[1], acc[2], acc[3]);
        }
    }
}

// ---------------------------------------------------------------------------
// omp: ONE WAVE per batch (64 threads), zero cross-wave sync. Lane owns 16
// atoms (8 x float2 proj registers: atoms 2*lane+128k, +1024 on lane 0).
// Winner: per-lane chain (ascending atom order, strict >) + DPP wave argmax
// with exact lowest-index tie-break. Rows staged in LDS (b64 conflict-free);
// border = per-lane rowsLds[lane][sel] + readlane broadcast (no bvec hop).
// Solve formulas identical to R12 (passing). Rolled i/j loops -> small code.
// One 1-wave __syncthreads per iter = lgkm drain for cross-lane visibility.
// ---------------------------------------------------------------------------
template <int NS>
__global__ __launch_bounds__(64)
void omp_kernel(const float* __restrict__ Gp, const float* __restrict__ PY,
                int* __restrict__ idxOut, float* __restrict__ wOut) {
    __shared__ float rowsLds[NNZ][RSTRIDE];   // 131,328 B, zero-init
    __shared__ float pyLds[NATOMS];
    __shared__ float diagLds[NATOMS];

    const int b = blockIdx.x;
    const int lane = threadIdx.x;

    float ainv[32];
#pragma unroll
    for (int m = 0; m < 32; ++m) ainv[m] = 0.f;
    float wvr = 0.f, rhsr = 0.f;
    int   myIdx = 0;

    // ---- init: zero rows; load py; diag from the NS partial diagonals
    {
        float4* rz = (float4*)&rowsLds[0][0];
        for (int u = lane; u < NNZ * RSTRIDE / 4; u += 64)
            rz[u] = make_float4(0.f, 0.f, 0.f, 0.f);
        const float* pyg = PY + (size_t)b * GSTRIDE;
        for (int u = lane; u < NATOMS; u += 64) {
            pyLds[u] = pyg[u];
            float d = 0.f;
#pragma unroll
            for (int z = 0; z < NS; ++z)
                d += Gp[(size_t)z * GELEMS + (size_t)u * (GSTRIDE + 1)];
            diagLds[u] = d;
        }
    }
    __syncthreads();

    // ---- proj registers
    float2 pr[8];
#pragma unroll
    for (int k = 0; k < 8; ++k)
        pr[k] = *(const float2*)&pyLds[2 * lane + 128 * k];
    float p1024 = (lane == 0) ? pyLds[1024] : 0.f;

    // ---- local + wave argmax (exact lowest-index tie-break)
    float bv; int sel;
    {
        bv = fabsf(pr[0].x); sel = 2 * lane;
        { float v = fabsf(pr[0].y); if (v > bv) { bv = v; sel = 2 * lane + 1; } }
#pragma unroll
        for (int k = 1; k < 8; ++k) {
            float vx = fabsf(pr[k].x);
            if (vx > bv) { bv = vx; sel = 2 * lane + 128 * k; }
            float vy = fabsf(pr[k].y);
            if (vy > bv) { bv = vy; sel = 2 * lane + 128 * k + 1; }
        }
        if (lane == 0) { float v = fabsf(p1024); if (v > bv) { bv = v; sel = 1024; } }
        wave_argmax64(bv, sel);
    }

    for (int i = 0; i < NNZ; ++i) {
        const float pysel = pyLds[sel];

        // ---- issue staging loads NOW (consumed after solve + j-loop)
        float2 sv[8]; float s1024 = 0.f;
#pragma unroll
        for (int k = 0; k < 8; ++k) sv[k] = make_float2(0.f, 0.f);
        if (i < NNZ - 1) {
            const size_t ro = (size_t)sel * GSTRIDE;
#pragma unroll
            for (int z = 0; z < NS; ++z) {
                const float* g = Gp + (size_t)z * GELEMS + ro;
#pragma unroll
                for (int k = 0; k < 8; ++k) {
                    const float2 t2 = *(const float2*)(g + 2 * lane + 128 * k);
                    sv[k].x += t2.x; sv[k].y += t2.y;
                }
                if (lane == 0) s1024 += g[1024];
            }
        }

        // ---- solve (in-wave, formulas identical to R12)
        const float bvl = (lane < 32) ? rowsLds[lane][sel] : 0.f;
        float u0 = 0.f, u1 = 0.f;
#pragma unroll
        for (int m = 0; m < 32; m += 2) {
            u0 = fmaf(ainv[m],     readlane_f(bvl, m),     u0);
            u1 = fmaf(ainv[m + 1], readlane_f(bvl, m + 1), u1);
        }
        const float uacc = u0 + u1;
        const float t = wave_sum64(bvl * uacc);
        const float s = wave_sum64(rhsr * uacc);
        const float dinv = 1.0f / (diagLds[sel] + REGL - t);
        const float beta = dinv * (pysel - s);
        const float uvb = (lane == i) ? -1.0f : uacc;   // lanes>=32: uacc==0
#pragma unroll
        for (int m = 0; m < 32; ++m)
            ainv[m] = fmaf(uvb * dinv, readlane_f(uvb, m), ainv[m]);
        wvr  = (lane == i) ? beta  : fmaf(-uacc, beta, wvr);
        rhsr = (lane == i) ? pysel : rhsr;
        if (lane == i) myIdx = sel;

        if (i == NNZ - 1) break;

        // ---- proj j-loop (LDS b64 conflict-free; j=i term via registers)
        float2 zz[8]; float z1024 = 0.f;
#pragma unroll
        for (int k = 0; k < 8; ++k) zz[k] = make_float2(0.f, 0.f);
        for (int j = 0; j < i; ++j) {
            const float uj = readlane_f(uvb, j);
#pragma unroll
            for (int k = 0; k < 8; ++k) {
                const float2 g = *(const float2*)&rowsLds[j][2 * lane + 128 * k];
                zz[k].x = fmaf(uj, g.x, zz[k].x);
                zz[k].y = fmaf(uj, g.y, zz[k].y);
            }
            if (lane == 0) z1024 = fmaf(uj, rowsLds[j][1024], z1024);
        }
#pragma unroll
        for (int k = 0; k < 8; ++k) {
            pr[k].x = fmaf(beta, zz[k].x, pr[k].x); pr[k].x = fmaf(-beta, sv[k].x, pr[k].x);
            pr[k].y = fmaf(beta, zz[k].y, pr[k].y); pr[k].y = fmaf(-beta, sv[k].y, pr[k].y);
        }
        if (lane == 0) { p1024 = fmaf(beta, z1024, p1024); p1024 = fmaf(-beta, s1024, p1024); }

        // ---- stage row i (after proj reads; visible next iter via sync)
#pragma unroll
        for (int k = 0; k < 8; ++k)
            *(float2*)&rowsLds[i][2 * lane + 128 * k] = sv[k];
        if (lane == 0) rowsLds[i][1024] = s1024;
        __syncthreads();                       // 1-wave lgkm drain

        // ---- abs-argmax for next iteration
        bv = fabsf(pr[0].x); sel = 2 * lane;
        { float v = fabsf(pr[0].y); if (v > bv) { bv = v; sel = 2 * lane + 1; } }
#pragma unroll
        for (int k = 1; k < 8; ++k) {
            float vx = fabsf(pr[k].x);
            if (vx > bv) { bv = vx; sel = 2 * lane + 128 * k; }
            float vy = fabsf(pr[k].y);
            if (vy > bv) { bv = vy; sel = 2 * lane + 128 * k + 1; }
        }
        if (lane == 0) { float v = fabsf(p1024); if (v > bv) { bv = v; sel = 1024; } }
        wave_argmax64(bv, sel);
    }

    if (lane < NNZ) {
        idxOut[b * NNZ + lane] = myIdx;
        wOut[b * NNZ + lane] = wvr;
    }
}

// ---------------------------------------------------------------------------
// recon (sparse): out[b][l] = sum_i X[b][l][widx_i]*wval_i + bias.
// Dup last-wins semantics preserved via dense scatter + gather-and-zero;
// atom 1024 (ones column) redirected into the bias.
// ---------------------------------------------------------------------------
__global__ __launch_bounds__(256)
void recon_kernel(const float* __restrict__ X, const int* __restrict__ idxIn,
                  const float* __restrict__ wIn, float* __restrict__ out) {
    __shared__ float Wd[1025];
    __shared__ float wval[NNZ];
    __shared__ int   widx[NNZ];
    __shared__ float biasS;
    const int b = blockIdx.x >> 2, chunk = blockIdx.x & 3;
    const int tid = threadIdx.x;
    for (int u = tid; u < 1025; u += 256) Wd[u] = 0.0f;
    __syncthreads();
    if (tid == 0) {
#pragma unroll
        for (int i = 0; i < NNZ; ++i) Wd[idxIn[b * NNZ + i]] = wIn[b * NNZ + i];
        float bias = 0.0f;
#pragma unroll
        for (int i = 0; i < NNZ; ++i) {
            const int gi = idxIn[b * NNZ + i];
            const float v = Wd[gi];
            Wd[gi] = 0.0f;                       // dup i reads 0 second time
            const bool isOnes = (gi == 1024);
            if (isOnes) bias += v;
            widx[i] = isOnes ? 0 : gi;
            wval[i] = isOnes ? 0.0f : v;
        }
        biasS = bias;
    }
    __syncthreads();
    const int l = chunk * 256 + tid;
    const float* __restrict__ xr = X + (size_t)b * 1024 * 1024 + (size_t)l * 1024;
    float a0 = biasS, a1 = 0.f, a2 = 0.f, a3 = 0.f;
#pragma unroll
    for (int i = 0; i < NNZ; i += 4) {
        a0 = fmaf(xr[widx[i + 0]], wval[i + 0], a0);
        a1 = fmaf(xr[widx[i + 1]], wval[i + 1], a1);
        a2 = fmaf(xr[widx[i + 2]], wval[i + 2], a2);
        a3 = fmaf(xr[widx[i + 3]], wval[i + 3], a3);
    }
    out[(size_t)b * 1024 + l] = (a0 + a1) + (a2 + a3);
}

// ---------------------------------------------------------------------------
extern "C" void kernel_launch(void* const* d_in, const int* in_sizes, int n_in,
                              void* d_out, int out_size, void* d_ws, size_t ws_size,
                              hipStream_t stream) {
    const float* X = (const float*)d_in[0];
    const float* y = (const float*)d_in[1];
    float* out = (float*)d_out;
    float* ws = (float*)d_ws;

    const size_t fixed = (size_t)64 * GSTRIDE + NBATCH * NNZ * 2 + 64;
    const size_t need4 = ((size_t)GELEMS * 4 + fixed) * sizeof(float);
    const int nsplit = (ws_size >= need4) ? 4 : 1;
    const int kLen = 1024 / nsplit;

    float* Gp = ws;
    float* PY = ws + (size_t)GELEMS * nsplit;
    float* wOut = PY + (size_t)64 * GSTRIDE;
    int* idxOut = (int*)(wOut + NBATCH * NNZ);

    gramprojy_kernel<<<dim3(9, 9, nsplit + 1), 256, 0, stream>>>(X, y, Gp, PY, kLen, nsplit);
    if (nsplit == 4) omp_kernel<4><<<NBATCH, 64, 0, stream>>>(Gp, PY, idxOut, wOut);
    else             omp_kernel<1><<<NBATCH, 64, 0, stream>>>(Gp, PY, idxOut, wOut);
    recon_kernel<<<NBATCH * 4, 256, 0, stream>>>(X, idxOut, wOut, out);
}

// Round 14
// 214.199 us; speedup vs baseline: 1.0581x; 1.0581x over previous
//
#include <hip/hip_runtime.h>
#include <math.h>

#define NATOMS   1025
#define GSTRIDE  1040               // padded row stride in Gp (floats)
#define GELEMS   (1025*GSTRIDE)
#define CSTRIDE  33                 // colT row stride: bank (a+j)%32, conflict-free
#define NNZ      32
#define NBATCH   64
#define REGL     0.0067153485f      // softplus(-5) in fp32

// DPP cross-lane helpers (VALU-latency, no LDS). old=0, bound_ctrl=false ->
// shifted-in lanes contribute (0, idx 0): harmless for abs-max / sum.
#define DPPF(x, ctrl) __int_as_float(__builtin_amdgcn_update_dpp(0, __float_as_int(x), (ctrl), 0xF, 0xF, false))

__device__ __forceinline__ float wave_sum64(float x) {
    x += DPPF(x, 0x111);
    x += DPPF(x, 0x112);
    x += DPPF(x, 0x114);
    x += DPPF(x, 0x118);
    x += DPPF(x, 0x142);
    x += DPPF(x, 0x143);
    return __int_as_float(__builtin_amdgcn_readlane(__float_as_int(x), 63));
}
__device__ __forceinline__ float readlane_f(float x, int l) {
    return __int_as_float(__builtin_amdgcn_readlane(__float_as_int(x), l));
}

// ---------------------------------------------------------------------------
// fused gram+projy. blockIdx.z < nsplit: gram (triangular bx<=by, 128x128 tile,
// 8x8/thread, split-K partial). Each partial is written FULLY SYMMETRIC:
// upper tile normally + mirrored tile via register float4 stores (bx!=by).
// blockIdx.z == nsplit: projy (64-atom x 16-batch tile).
// ---------------------------------------------------------------------------
__global__ __launch_bounds__(256)
void gramprojy_kernel(const float* __restrict__ X0, const float* __restrict__ y,
                      float* __restrict__ Gout, float* __restrict__ PY,
                      int kLen, int nsplit) {
    __shared__ float lds[8192];
    const int tid = threadIdx.x;

    if ((int)blockIdx.z < nsplit) {
        // ================= gram role =================
        const int bx = blockIdx.x, by = blockIdx.y, bz = blockIdx.z;
        if (by < bx) return;
        float* As = lds;            // [32][128]
        float* Bs = lds + 4096;     // [32][128]
        const int a0 = bx * 128, b0 = by * 128;
        float* __restrict__ Gp = Gout + (size_t)bz * GELEMS;
        const int tx = tid & 15;
        const int ty = tid >> 4;
        const int lr = tid >> 5;
        const int lc = (tid & 31) * 4;
        const bool aIn = (a0 + 128) <= 1024;
        const bool bIn = (b0 + 128) <= 1024;

        float acc[8][8];
#pragma unroll
        for (int m = 0; m < 8; ++m)
#pragma unroll
            for (int n = 0; n < 8; ++n) acc[m][n] = 0.0f;

        const int kBase = bz * kLen;
        for (int kc = 0; kc < kLen; kc += 32) {
#pragma unroll
            for (int rr = 0; rr < 4; ++rr) {
                const int r = lr + rr * 8;
                const int l = kBase + kc + r;
                if (aIn) {
                    *(float4*)&As[r * 128 + lc] = *(const float4*)&X0[(size_t)l * 1024 + a0 + lc];
                } else {
#pragma unroll
                    for (int k = 0; k < 4; ++k) {
                        const int col = a0 + lc + k;
                        As[r * 128 + lc + k] = (col < 1024) ? X0[(size_t)l * 1024 + col]
                                                            : (col == 1024 ? 1.0f : 0.0f);
                    }
                }
                if (bIn) {
                    *(float4*)&Bs[r * 128 + lc] = *(const float4*)&X0[(size_t)l * 1024 + b0 + lc];
                } else {
#pragma unroll
                    for (int k = 0; k < 4; ++k) {
                        const int col = b0 + lc + k;
                        Bs[r * 128 + lc + k] = (col < 1024) ? X0[(size_t)l * 1024 + col]
                                                            : (col == 1024 ? 1.0f : 0.0f);
                    }
                }
            }
            __syncthreads();
#pragma unroll 8
            for (int l = 0; l < 32; ++l) {
                float4 a01 = *(const float4*)&As[l * 128 + ty * 8];
                float4 a23 = *(const float4*)&As[l * 128 + ty * 8 + 4];
                float4 bA  = *(const float4*)&Bs[l * 128 + tx * 4];
                float4 bB  = *(const float4*)&Bs[l * 128 + 64 + tx * 4];
                float am[8] = {a01.x, a01.y, a01.z, a01.w, a23.x, a23.y, a23.z, a23.w};
                float bn[8] = {bA.x, bA.y, bA.z, bA.w, bB.x, bB.y, bB.z, bB.w};
#pragma unroll
                for (int m = 0; m < 8; ++m)
#pragma unroll
                    for (int n = 0; n < 8; ++n)
                        acc[m][n] += am[m] * bn[n];
            }
            __syncthreads();
        }

        // upper tile write (rows a, cols b)
#pragma unroll
        for (int m = 0; m < 8; ++m) {
            const int a = a0 + ty * 8 + m;
            if (a >= NATOMS) continue;
            const int bAc = b0 + tx * 4;
            const int bBc = b0 + 64 + tx * 4;
            if (bAc < GSTRIDE) {
                *(float4*)&Gp[(size_t)a * GSTRIDE + bAc] =
                    make_float4(acc[m][0], acc[m][1], acc[m][2], acc[m][3]);
            }
            if (bBc < GSTRIDE) {
                *(float4*)&Gp[(size_t)a * GSTRIDE + bBc] =
                    make_float4(acc[m][4], acc[m][5], acc[m][6], acc[m][7]);
            }
        }
        // mirror write (rows b, cols a), register float4s; bx<by => a-range <1024
        if (bx != by) {
#pragma unroll
            for (int n = 0; n < 8; ++n) {
                const int colg = b0 + ((n < 4) ? (tx * 4 + n) : (64 + tx * 4 + (n - 4)));
                if (colg >= NATOMS) continue;
                const int a = a0 + ty * 8;
                *(float4*)&Gp[(size_t)colg * GSTRIDE + a] =
                    make_float4(acc[0][n], acc[1][n], acc[2][n], acc[3][n]);
                *(float4*)&Gp[(size_t)colg * GSTRIDE + a + 4] =
                    make_float4(acc[4][n], acc[5][n], acc[6][n], acc[7][n]);
            }
        }
    } else {
        // ================= projy role =================
        const int pw = blockIdx.y * 9 + blockIdx.x;
        if (pw >= 68) return;
        const int a0 = (pw % 17) * 64;
        const int b0 = (pw / 17) * 16;
        float* Ds = lds;            // [32][64]
        float* Ys = lds + 2048;     // [32][17]
        const int tx = tid & 15;
        const int ty = tid >> 4;
        const bool aIn = (a0 + 64) <= 1024;

        float acc[4] = {0.0f, 0.0f, 0.0f, 0.0f};

        for (int kc = 0; kc < 1024; kc += 32) {
            {
                const int r  = tid >> 4;
                const int c4 = (tid & 15) * 4;
#pragma unroll
                for (int rr = 0; rr < 2; ++rr) {
                    const int row = r + rr * 16;
                    const int l = kc + row;
                    if (aIn) {
                        *(float4*)&Ds[row * 64 + c4] = *(const float4*)&X0[(size_t)l * 1024 + a0 + c4];
                    } else {
#pragma unroll
                        for (int k = 0; k < 4; ++k) {
                            const int col = a0 + c4 + k;
                            Ds[row * 64 + c4 + k] = (col < 1024) ? X0[(size_t)l * 1024 + col]
                                                                 : (col == 1024 ? 1.0f : 0.0f);
                        }
                    }
                }
            }
            for (int e = tid; e < 512; e += 256) {
                const int l = e & 31, bb = e >> 5;
                Ys[l * 17 + bb] = y[(size_t)(b0 + bb) * 1024 + kc + l];
            }
            __syncthreads();
#pragma unroll 8
            for (int l = 0; l < 32; ++l) {
                const float yv = Ys[l * 17 + ty];
                float4 dv = *(const float4*)&Ds[l * 64 + tx * 4];
                acc[0] += yv * dv.x; acc[1] += yv * dv.y;
                acc[2] += yv * dv.z; acc[3] += yv * dv.w;
            }
            __syncthreads();
        }
        const int a = a0 + tx * 4;
        if (a < GSTRIDE) {
            *(float4*)&PY[(size_t)(b0 + ty) * GSTRIDE + a] =
                make_float4(acc[0], acc[1], acc[2], acc[3]);
        }
    }
}

// ---------------------------------------------------------------------------
// omp: one wg/batch, 512 threads (8 waves), ONE barrier/iter, rolled body
// (small code; no I-cache pressure). Selected rows live TRANSPOSED in LDS:
// colT[a*33 + j] = G[sel_j][a]  -> writes (a+j)%32 conflict-free; border
// b[m] = colT[sel*33+m] is a broadcast read (no owner hop, no bvec).
// ainv in registers (row lane, statically unrolled); DPP reductions; staging
// loads issued after winner, vmcnt deferred past the j-loop. The intra-iter
// colT[.][i] write vs solve read race is benign: ainv row/col i is exactly 0
// until this iteration's rank-1 update (induction from zero-init).
// ---------------------------------------------------------------------------
template <int NS>
__global__ __launch_bounds__(512)
void omp_kernel(const float* __restrict__ Gp, const float* __restrict__ PY,
                int* __restrict__ idxOut, float* __restrict__ wOut) {
    __shared__ float colT[NATOMS * CSTRIDE];   // 135,300 B
    __shared__ float pyLds[1040];
    __shared__ float diagLds[1040];
    __shared__ float redV[2][8];
    __shared__ int   redI[2][8];

    const int b = blockIdx.x, tid = threadIdx.x;
    const int lane = tid & 63, wid = tid >> 6;

    float ainv[32];
#pragma unroll
    for (int m = 0; m < 32; ++m) ainv[m] = 0.f;
    float wvr = 0.f, rhsr = 0.f;
    int   myIdx = 0;

    // ---- init: zero colT; load py; diag from the NS partial diagonals
    {
        for (int u = tid; u < NATOMS * CSTRIDE; u += 512) colT[u] = 0.f;
        const float* pyg = PY + (size_t)b * GSTRIDE;
        pyLds[tid] = pyg[tid];
        pyLds[tid + 512] = pyg[tid + 512];
        if (tid < 16) pyLds[1024 + tid] = pyg[1024 + tid];
        float d0 = 0.f, d1 = 0.f, d2 = 0.f;
#pragma unroll
        for (int z = 0; z < NS; ++z) {
            const float* gz = Gp + (size_t)z * GELEMS;
            d0 += gz[(size_t)tid * (GSTRIDE + 1)];
            d1 += gz[(size_t)(tid + 512) * (GSTRIDE + 1)];
            if (tid == 511) d2 += gz[(size_t)1024 * (GSTRIDE + 1)];
        }
        diagLds[tid] = d0;
        diagLds[tid + 512] = d1;
        if (tid == 511) diagLds[1024] = d2;
    }
    __syncthreads();

    float p0 = pyLds[tid], p1 = pyLds[tid + 512];
    float p2 = (tid == 511) ? pyLds[1024] : 0.f;

    // ---- prologue argmax on |py| -> parity 0
    {
        float best = fabsf(p0); int bidx = tid;
        { float v = fabsf(p1); if (v > best) { best = v; bidx = tid + 512; } }
        if (tid == 511) { float v = fabsf(p2); if (v > best) { best = v; bidx = 1024; } }
        float wv_ = best; int wi_ = bidx;
#define AM_STEP(ctrl) {                                                        \
        float ov = DPPF(wv_, ctrl);                                            \
        int   oi = __builtin_amdgcn_update_dpp(0, wi_, (ctrl), 0xF, 0xF, false);\
        if (ov > wv_ || (ov == wv_ && oi < wi_)) { wv_ = ov; wi_ = oi; } }
        AM_STEP(0x111) AM_STEP(0x112) AM_STEP(0x114) AM_STEP(0x118)
        AM_STEP(0x142) AM_STEP(0x143)
        wv_ = readlane_f(wv_, 63);
        wi_ = __builtin_amdgcn_readlane(wi_, 63);
        if (lane == 0) { redV[0][wid] = wv_; redI[0][wid] = wi_; }
    }
    __syncthreads();

    for (int i = 0; i < NNZ; ++i) {
        const int par = i & 1;

        // ---- winner, replicated identically on all threads (broadcast reads)
        float bv_ = redV[par][0]; int sel = redI[par][0];
#pragma unroll
        for (int q = 1; q < 8; ++q) {
            if (redV[par][q] > bv_ || (redV[par][q] == bv_ && redI[par][q] < sel)) {
                bv_ = redV[par][q]; sel = redI[par][q];
            }
        }
        const float pysel = pyLds[sel];

        // ---- issue NS independent coalesced row loads (vmcnt after j-loop)
        float rA0 = 0.f, rA1 = 0.f, rA2 = 0.f, rA3 = 0.f;
        float rB0 = 0.f, rB1 = 0.f, rB2 = 0.f, rB3 = 0.f, rC = 0.f;
        if (i < NNZ - 1) {
            const size_t ro = (size_t)sel * GSTRIDE;
            { const float* g = Gp + ro;                      rA0 = g[tid]; rB0 = g[tid + 512]; }
            if (NS > 1) { const float* g = Gp + ro + (size_t)1 * GELEMS; rA1 = g[tid]; rB1 = g[tid + 512]; }
            if (NS > 2) { const float* g = Gp + ro + (size_t)2 * GELEMS; rA2 = g[tid]; rB2 = g[tid + 512]; }
            if (NS > 3) { const float* g = Gp + ro + (size_t)3 * GELEMS; rA3 = g[tid]; rB3 = g[tid + 512]; }
            if (tid == 511) {
#pragma unroll
                for (int z = 0; z < NS; ++z) rC += Gp[(size_t)z * GELEMS + ro + 1024];
            }
        }

        // ---- replicated solve: border from colT (broadcast), ainv in regs
        const float* csel = &colT[sel * CSTRIDE];
        const float bvl = (lane < 32) ? csel[lane] : 0.f;
        float u0 = 0.f, u1 = 0.f;
#pragma unroll
        for (int m = 0; m < 32; m += 2) {
            u0 = fmaf(ainv[m],     csel[m],     u0);
            u1 = fmaf(ainv[m + 1], csel[m + 1], u1);
        }
        const float uacc = u0 + u1;
        const float t = wave_sum64(bvl * uacc);
        const float s = wave_sum64(rhsr * uacc);
        const float dinv = 1.0f / (diagLds[sel] + REGL - t);
        const float beta = dinv * (pysel - s);
        const float uvb = (lane == i) ? -1.0f : uacc;   // lanes>=32: uacc==0
#pragma unroll
        for (int m = 0; m < 32; ++m)
            ainv[m] = fmaf(uvb * dinv, readlane_f(uvb, m), ainv[m]);
        wvr  = (lane == i) ? beta  : fmaf(-uacc, beta, wvr);
        rhsr = (lane == i) ? pysel : rhsr;
        if (tid == i) myIdx = sel;

        if (i == NNZ - 1) break;

        // ---- proj j-loop from colT (rolled; (tid+j)%32 conflict-free)
        float z0 = 0.f, z1 = 0.f, z2 = 0.f;
        const float* c0 = &colT[tid * CSTRIDE];
        const float* c1 = &colT[(tid + 512) * CSTRIDE];
        for (int j = 0; j < i; ++j) {
            const float uj = readlane_f(uvb, j);
            z0 = fmaf(uj, c0[j], z0);
            z1 = fmaf(uj, c1[j], z1);
            if (tid == 511) z2 = fmaf(uj, colT[1024 * CSTRIDE + j], z2);
        }
        // ---- consume staged loads (vmcnt waits here, hidden under solve+jloop)
        const float r0 = (rA0 + rA1) + (rA2 + rA3);
        const float r1 = (rB0 + rB1) + (rB2 + rB3);
        p0 = fmaf(beta, z0, p0); p0 = fmaf(-beta, r0, p0);
        p1 = fmaf(beta, z1, p1); p1 = fmaf(-beta, r1, p1);
        if (tid == 511) { p2 = fmaf(beta, z2, p2); p2 = fmaf(-beta, rC, p2); }

        // ---- stage row i transposed (after own proj reads; benign vs solve)
        colT[tid * CSTRIDE + i] = r0;
        colT[(tid + 512) * CSTRIDE + i] = r1;
        if (tid == 511) colT[1024 * CSTRIDE + i] = rC;

        // ---- abs-argmax -> other parity
        {
            float best = fabsf(p0); int bidx = tid;
            { float v = fabsf(p1); if (v > best) { best = v; bidx = tid + 512; } }
            if (tid == 511) { float v = fabsf(p2); if (v > best) { best = v; bidx = 1024; } }
            float wv_ = best; int wi_ = bidx;
            AM_STEP(0x111) AM_STEP(0x112) AM_STEP(0x114) AM_STEP(0x118)
            AM_STEP(0x142) AM_STEP(0x143)
            wv_ = readlane_f(wv_, 63);
            wi_ = __builtin_amdgcn_readlane(wi_, 63);
            if (lane == 0) { redV[par ^ 1][wid] = wv_; redI[par ^ 1][wid] = wi_; }
        }
        __syncthreads();                                 // the ONE barrier
    }
#undef AM_STEP

    if (tid < NNZ) {
        idxOut[b * NNZ + tid] = myIdx;
        wOut[b * NNZ + tid] = wvr;
    }
}

// ---------------------------------------------------------------------------
// recon (sparse): out[b][l] = sum_i X[b][l][widx_i]*wval_i + bias.
// Dup last-wins semantics preserved via dense scatter + gather-and-zero;
// atom 1024 (ones column) redirected into the bias.
// ---------------------------------------------------------------------------
__global__ __launch_bounds__(256)
void recon_kernel(const float* __restrict__ X, const int* __restrict__ idxIn,
                  const float* __restrict__ wIn, float* __restrict__ out) {
    __shared__ float Wd[1025];
    __shared__ float wval[NNZ];
    __shared__ int   widx[NNZ];
    __shared__ float biasS;
    const int b = blockIdx.x >> 2, chunk = blockIdx.x & 3;
    const int tid = threadIdx.x;
    for (int u = tid; u < 1025; u += 256) Wd[u] = 0.0f;
    __syncthreads();
    if (tid == 0) {
#pragma unroll
        for (int i = 0; i < NNZ; ++i) Wd[idxIn[b * NNZ + i]] = wIn[b * NNZ + i];
        float bias = 0.0f;
#pragma unroll
        for (int i = 0; i < NNZ; ++i) {
            const int gi = idxIn[b * NNZ + i];
            const float v = Wd[gi];
            Wd[gi] = 0.0f;                       // dup i reads 0 second time
            const bool isOnes = (gi == 1024);
            if (isOnes) bias += v;
            widx[i] = isOnes ? 0 : gi;
            wval[i] = isOnes ? 0.0f : v;
        }
        biasS = bias;
    }
    __syncthreads();
    const int l = chunk * 256 + tid;
    const float* __restrict__ xr = X + (size_t)b * 1024 * 1024 + (size_t)l * 1024;
    float a0 = biasS, a1 = 0.f, a2 = 0.f, a3 = 0.f;
#pragma unroll
    for (int i = 0; i < NNZ; i += 4) {
        a0 = fmaf(xr[widx[i + 0]], wval[i + 0], a0);
        a1 = fmaf(xr[widx[i + 1]], wval[i + 1], a1);
        a2 = fmaf(xr[widx[i + 2]], wval[i + 2], a2);
        a3 = fmaf(xr[widx[i + 3]], wval[i + 3], a3);
    }
    out[(size_t)b * 1024 + l] = (a0 + a1) + (a2 + a3);
}

// ---------------------------------------------------------------------------
extern "C" void kernel_launch(void* const* d_in, const int* in_sizes, int n_in,
                              void* d_out, int out_size, void* d_ws, size_t ws_size,
                              hipStream_t stream) {
    const float* X = (const float*)d_in[0];
    const float* y = (const float*)d_in[1];
    float* out = (float*)d_out;
    float* ws = (float*)d_ws;

    const size_t fixed = (size_t)64 * GSTRIDE + NBATCH * NNZ * 2 + 64;
    const size_t need4 = ((size_t)GELEMS * 4 + fixed) * sizeof(float);
    const int nsplit = (ws_size >= need4) ? 4 : 1;
    const int kLen = 1024 / nsplit;

    float* Gp = ws;
    float* PY = ws + (size_t)GELEMS * nsplit;
    float* wOut = PY + (size_t)64 * GSTRIDE;
    int* idxOut = (int*)(wOut + NBATCH * NNZ);

    gramprojy_kernel<<<dim3(9, 9, nsplit + 1), 256, 0, stream>>>(X, y, Gp, PY, kLen, nsplit);
    if (nsplit == 4) omp_kernel<4><<<NBATCH, 512, 0, stream>>>(Gp, PY, idxOut, wOut);
    else             omp_kernel<1><<<NBATCH, 512, 0, stream>>>(Gp, PY, idxOut, wOut);
    recon_kernel<<<NBATCH * 4, 256, 0, stream>>>(X, idxOut, wOut, out);
}

// Round 15
// 187.172 us; speedup vs baseline: 1.2109x; 1.1444x over previous
//
#include <hip/hip_runtime.h>
#include <math.h>

#define NATOMS   1025
#define GSTRIDE  1040               // padded row stride in Gp (floats)
#define GELEMS   (1025*GSTRIDE)
#define CSTRIDE  33                 // colT row stride: bank (a+j)%32, conflict-free
#define NNZ      32
#define NBATCH   64
#define REGL     0.0067153485f      // softplus(-5) in fp32

// DPP cross-lane helpers (VALU-latency, no LDS). old=0, bound_ctrl=false ->
// shifted-in lanes contribute (0, idx 0): harmless for abs-max / sum.
#define DPPF(x, ctrl) __int_as_float(__builtin_amdgcn_update_dpp(0, __float_as_int(x), (ctrl), 0xF, 0xF, false))

__device__ __forceinline__ float wave_sum64(float x) {
    x += DPPF(x, 0x111);
    x += DPPF(x, 0x112);
    x += DPPF(x, 0x114);
    x += DPPF(x, 0x118);
    x += DPPF(x, 0x142);
    x += DPPF(x, 0x143);
    return __int_as_float(__builtin_amdgcn_readlane(__float_as_int(x), 63));
}
__device__ __forceinline__ float readlane_f(float x, int l) {
    return __int_as_float(__builtin_amdgcn_readlane(__float_as_int(x), l));
}

// ---------------------------------------------------------------------------
// fused gram+projy. blockIdx.z < nsplit: gram (triangular bx<=by, 128x128 tile,
// 8x8/thread, split-K partial). Each partial is written FULLY SYMMETRIC:
// upper tile normally + mirrored tile via register float4 stores (bx!=by).
// blockIdx.z == nsplit: projy (64-atom x 16-batch tile).
// ---------------------------------------------------------------------------
__global__ __launch_bounds__(256)
void gramprojy_kernel(const float* __restrict__ X0, const float* __restrict__ y,
                      float* __restrict__ Gout, float* __restrict__ PY,
                      int kLen, int nsplit) {
    __shared__ float lds[8192];
    const int tid = threadIdx.x;

    if ((int)blockIdx.z < nsplit) {
        // ================= gram role =================
        const int bx = blockIdx.x, by = blockIdx.y, bz = blockIdx.z;
        if (by < bx) return;
        float* As = lds;            // [32][128]
        float* Bs = lds + 4096;     // [32][128]
        const int a0 = bx * 128, b0 = by * 128;
        float* __restrict__ Gp = Gout + (size_t)bz * GELEMS;
        const int tx = tid & 15;
        const int ty = tid >> 4;
        const int lr = tid >> 5;
        const int lc = (tid & 31) * 4;
        const bool aIn = (a0 + 128) <= 1024;
        const bool bIn = (b0 + 128) <= 1024;

        float acc[8][8];
#pragma unroll
        for (int m = 0; m < 8; ++m)
#pragma unroll
            for (int n = 0; n < 8; ++n) acc[m][n] = 0.0f;

        const int kBase = bz * kLen;
        for (int kc = 0; kc < kLen; kc += 32) {
#pragma unroll
            for (int rr = 0; rr < 4; ++rr) {
                const int r = lr + rr * 8;
                const int l = kBase + kc + r;
                if (aIn) {
                    *(float4*)&As[r * 128 + lc] = *(const float4*)&X0[(size_t)l * 1024 + a0 + lc];
                } else {
#pragma unroll
                    for (int k = 0; k < 4; ++k) {
                        const int col = a0 + lc + k;
                        As[r * 128 + lc + k] = (col < 1024) ? X0[(size_t)l * 1024 + col]
                                                            : (col == 1024 ? 1.0f : 0.0f);
                    }
                }
                if (bIn) {
                    *(float4*)&Bs[r * 128 + lc] = *(const float4*)&X0[(size_t)l * 1024 + b0 + lc];
                } else {
#pragma unroll
                    for (int k = 0; k < 4; ++k) {
                        const int col = b0 + lc + k;
                        Bs[r * 128 + lc + k] = (col < 1024) ? X0[(size_t)l * 1024 + col]
                                                            : (col == 1024 ? 1.0f : 0.0f);
                    }
                }
            }
            __syncthreads();
#pragma unroll 8
            for (int l = 0; l < 32; ++l) {
                float4 a01 = *(const float4*)&As[l * 128 + ty * 8];
                float4 a23 = *(const float4*)&As[l * 128 + ty * 8 + 4];
                float4 bA  = *(const float4*)&Bs[l * 128 + tx * 4];
                float4 bB  = *(const float4*)&Bs[l * 128 + 64 + tx * 4];
                float am[8] = {a01.x, a01.y, a01.z, a01.w, a23.x, a23.y, a23.z, a23.w};
                float bn[8] = {bA.x, bA.y, bA.z, bA.w, bB.x, bB.y, bB.z, bB.w};
#pragma unroll
                for (int m = 0; m < 8; ++m)
#pragma unroll
                    for (int n = 0; n < 8; ++n)
                        acc[m][n] += am[m] * bn[n];
            }
            __syncthreads();
        }

        // upper tile write (rows a, cols b)
#pragma unroll
        for (int m = 0; m < 8; ++m) {
            const int a = a0 + ty * 8 + m;
            if (a >= NATOMS) continue;
            const int bAc = b0 + tx * 4;
            const int bBc = b0 + 64 + tx * 4;
            if (bAc < GSTRIDE) {
                *(float4*)&Gp[(size_t)a * GSTRIDE + bAc] =
                    make_float4(acc[m][0], acc[m][1], acc[m][2], acc[m][3]);
            }
            if (bBc < GSTRIDE) {
                *(float4*)&Gp[(size_t)a * GSTRIDE + bBc] =
                    make_float4(acc[m][4], acc[m][5], acc[m][6], acc[m][7]);
            }
        }
        // mirror write (rows b, cols a), register float4s; bx<by => a-range <1024
        if (bx != by) {
#pragma unroll
            for (int n = 0; n < 8; ++n) {
                const int colg = b0 + ((n < 4) ? (tx * 4 + n) : (64 + tx * 4 + (n - 4)));
                if (colg >= NATOMS) continue;
                const int a = a0 + ty * 8;
                *(float4*)&Gp[(size_t)colg * GSTRIDE + a] =
                    make_float4(acc[0][n], acc[1][n], acc[2][n], acc[3][n]);
                *(float4*)&Gp[(size_t)colg * GSTRIDE + a + 4] =
                    make_float4(acc[4][n], acc[5][n], acc[6][n], acc[7][n]);
            }
        }
    } else {
        // ================= projy role =================
        const int pw = blockIdx.y * 9 + blockIdx.x;
        if (pw >= 68) return;
        const int a0 = (pw % 17) * 64;
        const int b0 = (pw / 17) * 16;
        float* Ds = lds;            // [32][64]
        float* Ys = lds + 2048;     // [32][17]
        const int tx = tid & 15;
        const int ty = tid >> 4;
        const bool aIn = (a0 + 64) <= 1024;

        float acc[4] = {0.0f, 0.0f, 0.0f, 0.0f};

        for (int kc = 0; kc < 1024; kc += 32) {
            {
                const int r  = tid >> 4;
                const int c4 = (tid & 15) * 4;
#pragma unroll
                for (int rr = 0; rr < 2; ++rr) {
                    const int row = r + rr * 16;
                    const int l = kc + row;
                    if (aIn) {
                        *(float4*)&Ds[row * 64 + c4] = *(const float4*)&X0[(size_t)l * 1024 + a0 + c4];
                    } else {
#pragma unroll
                        for (int k = 0; k < 4; ++k) {
                            const int col = a0 + c4 + k;
                            Ds[row * 64 + c4 + k] = (col < 1024) ? X0[(size_t)l * 1024 + col]
                                                                 : (col == 1024 ? 1.0f : 0.0f);
                        }
                    }
                }
            }
            for (int e = tid; e < 512; e += 256) {
                const int l = e & 31, bb = e >> 5;
                Ys[l * 17 + bb] = y[(size_t)(b0 + bb) * 1024 + kc + l];
            }
            __syncthreads();
#pragma unroll 8
            for (int l = 0; l < 32; ++l) {
                const float yv = Ys[l * 17 + ty];
                float4 dv = *(const float4*)&Ds[l * 64 + tx * 4];
                acc[0] += yv * dv.x; acc[1] += yv * dv.y;
                acc[2] += yv * dv.z; acc[3] += yv * dv.w;
            }
            __syncthreads();
        }
        const int a = a0 + tx * 4;
        if (a < GSTRIDE) {
            *(float4*)&PY[(size_t)(b0 + ty) * GSTRIDE + a] =
                make_float4(acc[0], acc[1], acc[2], acc[3]);
        }
    }
}

// ---------------------------------------------------------------------------
// omp hybrid (R12 regs + R14 colT border): one wg/batch, 512 threads (8 waves),
// ONE barrier/iter. Rows in REGISTERS rr0/rr1 (macro-stamped static indexing)
// for the j-loop; rows ALSO written transposed to colT[a*33+j] so the border
// b[m] = colT[sel*33+m] is a broadcast read (no owner 32-store hop, no bvec
// barrier). Intra-iter colT[.][i] write vs solve read race is benign: ainv
// row/col i is structurally zero until this iteration's rank-1 update (LDS 4B
// writes are atomic -> garbage is a finite float times exact 0).
// Staging loads issue after winner; vmcnt deferred past the j-loop.
// ---------------------------------------------------------------------------
template <int NS>
__global__ __launch_bounds__(512)
void omp_kernel(const float* __restrict__ Gp, const float* __restrict__ PY,
                int* __restrict__ idxOut, float* __restrict__ wOut) {
    __shared__ float colT[NATOMS * CSTRIDE];   // 135,300 B
    __shared__ float pyLds[1040];
    __shared__ float diagLds[1040];
    __shared__ float redV[2][8];
    __shared__ int   redI[2][8];

    const int b = blockIdx.x, tid = threadIdx.x;
    const int lane = tid & 63, wid = tid >> 6;

    float rr0[NNZ], rr1[NNZ];     // my two atoms of every staged row
    float ainv[32];
#pragma unroll
    for (int m = 0; m < 32; ++m) { ainv[m] = 0.f; rr0[m] = 0.f; rr1[m] = 0.f; }
    float wvr = 0.f, rhsr = 0.f;
    int   myIdx = 0;

    // ---- init: zero colT; load py; diag from the NS partial diagonals
    {
        for (int u = tid; u < NATOMS * CSTRIDE; u += 512) colT[u] = 0.f;
        const float* pyg = PY + (size_t)b * GSTRIDE;
        pyLds[tid] = pyg[tid];
        pyLds[tid + 512] = pyg[tid + 512];
        if (tid < 16) pyLds[1024 + tid] = pyg[1024 + tid];
        float d0 = 0.f, d1 = 0.f, d2 = 0.f;
#pragma unroll
        for (int z = 0; z < NS; ++z) {
            const float* gz = Gp + (size_t)z * GELEMS;
            d0 += gz[(size_t)tid * (GSTRIDE + 1)];
            d1 += gz[(size_t)(tid + 512) * (GSTRIDE + 1)];
            if (tid == 511) d2 += gz[(size_t)1024 * (GSTRIDE + 1)];
        }
        diagLds[tid] = d0;
        diagLds[tid + 512] = d1;
        if (tid == 511) diagLds[1024] = d2;
    }
    __syncthreads();

    float p0 = pyLds[tid], p1 = pyLds[tid + 512];
    float p2 = (tid == 511) ? pyLds[1024] : 0.f;

    // ---- prologue argmax on |py| -> parity 0
#define AM_STEP(ctrl) {                                                        \
        float ov = DPPF(wv_, ctrl);                                            \
        int   oi = __builtin_amdgcn_update_dpp(0, wi_, (ctrl), 0xF, 0xF, false);\
        if (ov > wv_ || (ov == wv_ && oi < wi_)) { wv_ = ov; wi_ = oi; } }
    {
        float best = fabsf(p0); int bidx = tid;
        { float v = fabsf(p1); if (v > best) { best = v; bidx = tid + 512; } }
        if (tid == 511) { float v = fabsf(p2); if (v > best) { best = v; bidx = 1024; } }
        float wv_ = best; int wi_ = bidx;
        AM_STEP(0x111) AM_STEP(0x112) AM_STEP(0x114) AM_STEP(0x118)
        AM_STEP(0x142) AM_STEP(0x143)
        wv_ = readlane_f(wv_, 63);
        wi_ = __builtin_amdgcn_readlane(wi_, 63);
        if (lane == 0) { redV[0][wid] = wv_; redI[0][wid] = wi_; }
    }
    __syncthreads();

    // ================= macro-stamped main loop (static register indexing) ====
#define OMP_ITER(I)                                                            \
    {                                                                          \
        const int par = (I) & 1;                                               \
        float bv_ = redV[par][0]; int sel = redI[par][0];                      \
        _Pragma("unroll")                                                      \
        for (int q = 1; q < 8; ++q) {                                          \
            if (redV[par][q] > bv_ ||                                          \
                (redV[par][q] == bv_ && redI[par][q] < sel)) {                 \
                bv_ = redV[par][q]; sel = redI[par][q];                        \
            }                                                                  \
        }                                                                      \
        const float pysel = pyLds[sel];                                        \
        float rA0=0.f,rA1=0.f,rA2=0.f,rA3=0.f;                                 \
        float rB0=0.f,rB1=0.f,rB2=0.f,rB3=0.f,rC=0.f;                          \
        if ((I) < NNZ - 1) {                                                   \
            const size_t ro = (size_t)sel * GSTRIDE;                           \
            { const float* g = Gp + ro; rA0 = g[tid]; rB0 = g[tid + 512]; }    \
            if (NS > 1) { const float* g = Gp + ro + (size_t)1 * GELEMS;       \
                          rA1 = g[tid]; rB1 = g[tid + 512]; }                  \
            if (NS > 2) { const float* g = Gp + ro + (size_t)2 * GELEMS;       \
                          rA2 = g[tid]; rB2 = g[tid + 512]; }                  \
            if (NS > 3) { const float* g = Gp + ro + (size_t)3 * GELEMS;       \
                          rA3 = g[tid]; rB3 = g[tid + 512]; }                  \
            if (tid == 511) {                                                  \
                _Pragma("unroll")                                              \
                for (int z = 0; z < NS; ++z)                                   \
                    rC += Gp[(size_t)z * GELEMS + ro + 1024];                  \
            }                                                                  \
        }                                                                      \
        const float* csel = &colT[sel * CSTRIDE];                              \
        const float bvl = (lane < 32) ? csel[lane] : 0.f;                      \
        float u0 = 0.f, u1 = 0.f;                                              \
        _Pragma("unroll")                                                      \
        for (int m = 0; m < 32; m += 2) {                                      \
            u0 = fmaf(ainv[m],     csel[m],     u0);                           \
            u1 = fmaf(ainv[m + 1], csel[m + 1], u1);                           \
        }                                                                      \
        const float uacc = u0 + u1;                                            \
        const float t = wave_sum64(bvl * uacc);                                \
        const float s = wave_sum64(rhsr * uacc);                               \
        const float dinv = 1.0f / (diagLds[sel] + REGL - t);                   \
        const float beta = dinv * (pysel - s);                                 \
        const float uvb = (lane == (I)) ? -1.0f : uacc;                        \
        _Pragma("unroll")                                                      \
        for (int m = 0; m < 32; ++m)                                           \
            ainv[m] = fmaf(uvb * dinv, readlane_f(uvb, m), ainv[m]);           \
        wvr  = (lane == (I)) ? beta  : fmaf(-uacc, beta, wvr);                 \
        rhsr = (lane == (I)) ? pysel : rhsr;                                   \
        if (tid == (I)) myIdx = sel;                                           \
        if ((I) < NNZ - 1) {                                                   \
            float z0 = 0.f, z1 = 0.f, z2 = 0.f;                                \
            _Pragma("unroll")                                                  \
            for (int j = 0; j < NNZ - 1; ++j) {                                \
                if (j < (I)) {                                                 \
                    const float uj = readlane_f(uvb, j);                       \
                    z0 = fmaf(uj, rr0[j], z0);                                 \
                    z1 = fmaf(uj, rr1[j], z1);                                 \
                    if (tid == 511) z2 = fmaf(uj, colT[1024 * CSTRIDE + j], z2); \
                }                                                              \
            }                                                                  \
            const float r0 = (rA0 + rA1) + (rA2 + rA3);                        \
            const float r1 = (rB0 + rB1) + (rB2 + rB3);                        \
            p0 = fmaf(beta, z0, p0); p0 = fmaf(-beta, r0, p0);                 \
            p1 = fmaf(beta, z1, p1); p1 = fmaf(-beta, r1, p1);                 \
            if (tid == 511) { p2 = fmaf(beta, z2, p2);                         \
                              p2 = fmaf(-beta, rC, p2); }                      \
            rr0[(I)] = r0; rr1[(I)] = r1;                                      \
            colT[tid * CSTRIDE + (I)] = r0;                                    \
            colT[(tid + 512) * CSTRIDE + (I)] = r1;                            \
            if (tid == 511) colT[1024 * CSTRIDE + (I)] = rC;                   \
            float best = fabsf(p0); int bidx = tid;                            \
            { float v = fabsf(p1); if (v > best) { best = v; bidx = tid + 512; } } \
            if (tid == 511) { float v = fabsf(p2);                             \
                              if (v > best) { best = v; bidx = 1024; } }       \
            float wv_ = best; int wi_ = bidx;                                  \
            AM_STEP(0x111) AM_STEP(0x112) AM_STEP(0x114) AM_STEP(0x118)       \
            AM_STEP(0x142) AM_STEP(0x143)                                      \
            wv_ = readlane_f(wv_, 63);                                         \
            wi_ = __builtin_amdgcn_readlane(wi_, 63);                          \
            if (lane == 0) { redV[par ^ 1][wid] = wv_;                         \
                             redI[par ^ 1][wid] = wi_; }                       \
            __syncthreads();                 /* the ONE barrier */             \
        }                                                                      \
    }

    OMP_ITER(0)  OMP_ITER(1)  OMP_ITER(2)  OMP_ITER(3)
    OMP_ITER(4)  OMP_ITER(5)  OMP_ITER(6)  OMP_ITER(7)
    OMP_ITER(8)  OMP_ITER(9)  OMP_ITER(10) OMP_ITER(11)
    OMP_ITER(12) OMP_ITER(13) OMP_ITER(14) OMP_ITER(15)
    OMP_ITER(16) OMP_ITER(17) OMP_ITER(18) OMP_ITER(19)
    OMP_ITER(20) OMP_ITER(21) OMP_ITER(22) OMP_ITER(23)
    OMP_ITER(24) OMP_ITER(25) OMP_ITER(26) OMP_ITER(27)
    OMP_ITER(28) OMP_ITER(29) OMP_ITER(30) OMP_ITER(31)
#undef OMP_ITER
#undef AM_STEP

    if (tid < NNZ) {
        idxOut[b * NNZ + tid] = myIdx;
        wOut[b * NNZ + tid] = wvr;
    }
}

// ---------------------------------------------------------------------------
// recon (dense, coalesced): out[b][l] = sum_a X[b][l][a]*W[b][a] + W[b][1024].
// W built dense in LDS with sequential last-wins scatter (matches .at[].set).
// 268 MB coalesced float4 stream (beats the 64B-line sparse gather).
// ---------------------------------------------------------------------------
__global__ __launch_bounds__(256)
void recon_kernel(const float* __restrict__ X, const int* __restrict__ idxIn,
                  const float* __restrict__ wIn, float* __restrict__ out) {
    __shared__ float4 Wd4[260];          // 1040 floats
    const int b = blockIdx.x >> 3, chunk = blockIdx.x & 7;
    const int tid = threadIdx.x, lane = tid & 63, wid = tid >> 6;
    float* Wd = (float*)Wd4;
    for (int u = tid; u < 1040; u += 256) Wd[u] = 0.0f;
    __syncthreads();
    if (tid == 0) {
#pragma unroll
        for (int i = 0; i < NNZ; ++i) Wd[idxIn[b * NNZ + i]] = wIn[b * NNZ + i];
    }
    __syncthreads();
    const float wOne = Wd[1024];
    const float* Xb = X + (size_t)b * 1024 * 1024;

    for (int rr = wid; rr < 128; rr += 4) {
        const int r = chunk * 128 + rr;
        const float4* xr = (const float4*)(Xb + (size_t)r * 1024);
        float acc = 0.0f;
#pragma unroll
        for (int q = 0; q < 4; ++q) {
            float4 x = xr[q * 64 + lane];
            float4 w = Wd4[q * 64 + lane];
            acc += x.x * w.x + x.y * w.y + x.z * w.z + x.w * w.w;
        }
        acc = wave_sum64(acc);
        if (lane == 0) out[(size_t)b * 1024 + r] = acc + wOne;
    }
}

// ---------------------------------------------------------------------------
extern "C" void kernel_launch(void* const* d_in, const int* in_sizes, int n_in,
                              void* d_out, int out_size, void* d_ws, size_t ws_size,
                              hipStream_t stream) {
    const float* X = (const float*)d_in[0];
    const float* y = (const float*)d_in[1];
    float* out = (float*)d_out;
    float* ws = (float*)d_ws;

    const size_t fixed = (size_t)64 * GSTRIDE + NBATCH * NNZ * 2 + 64;
    const size_t need4 = ((size_t)GELEMS * 4 + fixed) * sizeof(float);
    const int nsplit = (ws_size >= need4) ? 4 : 1;
    const int kLen = 1024 / nsplit;

    float* Gp = ws;
    float* PY = ws + (size_t)GELEMS * nsplit;
    float* wOut = PY + (size_t)64 * GSTRIDE;
    int* idxOut = (int*)(wOut + NBATCH * NNZ);

    gramprojy_kernel<<<dim3(9, 9, nsplit + 1), 256, 0, stream>>>(X, y, Gp, PY, kLen, nsplit);
    if (nsplit == 4) omp_kernel<4><<<NBATCH, 512, 0, stream>>>(Gp, PY, idxOut, wOut);
    else             omp_kernel<1><<<NBATCH, 512, 0, stream>>>(Gp, PY, idxOut, wOut);
    recon_kernel<<<NBATCH * 8, 256, 0, stream>>>(X, idxOut, wOut, out);
}

// Round 16
// 183.180 us; speedup vs baseline: 1.2373x; 1.0218x over previous
//
#include <hip/hip_runtime.h>
#include <math.h>

#define NATOMS   1025
#define GSTRIDE  1040               // padded row stride in Gp (floats)
#define GELEMS   (1025*GSTRIDE)
#define CSTRIDE  33                 // colT row stride: bank (a+j)%32, conflict-free
#define NNZ      32
#define NBATCH   64
#define REGL     0.0067153485f      // softplus(-5) in fp32

// DPP cross-lane helpers (VALU-latency, no LDS). old=0, bound_ctrl=false ->
// shifted-in lanes contribute (0, idx 0): harmless for abs-max / sum.
#define DPPF(x, ctrl) __int_as_float(__builtin_amdgcn_update_dpp(0, __float_as_int(x), (ctrl), 0xF, 0xF, false))

__device__ __forceinline__ float wave_sum64(float x) {
    x += DPPF(x, 0x111);
    x += DPPF(x, 0x112);
    x += DPPF(x, 0x114);
    x += DPPF(x, 0x118);
    x += DPPF(x, 0x142);
    x += DPPF(x, 0x143);
    return __int_as_float(__builtin_amdgcn_readlane(__float_as_int(x), 63));
}
__device__ __forceinline__ float readlane_f(float x, int l) {
    return __int_as_float(__builtin_amdgcn_readlane(__float_as_int(x), l));
}

// ---------------------------------------------------------------------------
// fused gram+projy. blockIdx.z < nsplit: gram (triangular bx<=by, 128x128 tile,
// 8x8/thread, split-K partial). Each partial is written FULLY SYMMETRIC:
// upper tile normally + mirrored tile via register float4 stores (bx!=by).
// blockIdx.z == nsplit: projy (64-atom x 16-batch tile).
// ---------------------------------------------------------------------------
__global__ __launch_bounds__(256)
void gramprojy_kernel(const float* __restrict__ X0, const float* __restrict__ y,
                      float* __restrict__ Gout, float* __restrict__ PY,
                      int kLen, int nsplit) {
    __shared__ float lds[8192];
    const int tid = threadIdx.x;

    if ((int)blockIdx.z < nsplit) {
        // ================= gram role =================
        const int bx = blockIdx.x, by = blockIdx.y, bz = blockIdx.z;
        if (by < bx) return;
        float* As = lds;            // [32][128]
        float* Bs = lds + 4096;     // [32][128]
        const int a0 = bx * 128, b0 = by * 128;
        float* __restrict__ Gp = Gout + (size_t)bz * GELEMS;
        const int tx = tid & 15;
        const int ty = tid >> 4;
        const int lr = tid >> 5;
        const int lc = (tid & 31) * 4;
        const bool aIn = (a0 + 128) <= 1024;
        const bool bIn = (b0 + 128) <= 1024;

        float acc[8][8];
#pragma unroll
        for (int m = 0; m < 8; ++m)
#pragma unroll
            for (int n = 0; n < 8; ++n) acc[m][n] = 0.0f;

        const int kBase = bz * kLen;
        for (int kc = 0; kc < kLen; kc += 32) {
#pragma unroll
            for (int rr = 0; rr < 4; ++rr) {
                const int r = lr + rr * 8;
                const int l = kBase + kc + r;
                if (aIn) {
                    *(float4*)&As[r * 128 + lc] = *(const float4*)&X0[(size_t)l * 1024 + a0 + lc];
                } else {
#pragma unroll
                    for (int k = 0; k < 4; ++k) {
                        const int col = a0 + lc + k;
                        As[r * 128 + lc + k] = (col < 1024) ? X0[(size_t)l * 1024 + col]
                                                            : (col == 1024 ? 1.0f : 0.0f);
                    }
                }
                if (bIn) {
                    *(float4*)&Bs[r * 128 + lc] = *(const float4*)&X0[(size_t)l * 1024 + b0 + lc];
                } else {
#pragma unroll
                    for (int k = 0; k < 4; ++k) {
                        const int col = b0 + lc + k;
                        Bs[r * 128 + lc + k] = (col < 1024) ? X0[(size_t)l * 1024 + col]
                                                            : (col == 1024 ? 1.0f : 0.0f);
                    }
                }
            }
            __syncthreads();
#pragma unroll 8
            for (int l = 0; l < 32; ++l) {
                float4 a01 = *(const float4*)&As[l * 128 + ty * 8];
                float4 a23 = *(const float4*)&As[l * 128 + ty * 8 + 4];
                float4 bA  = *(const float4*)&Bs[l * 128 + tx * 4];
                float4 bB  = *(const float4*)&Bs[l * 128 + 64 + tx * 4];
                float am[8] = {a01.x, a01.y, a01.z, a01.w, a23.x, a23.y, a23.z, a23.w};
                float bn[8] = {bA.x, bA.y, bA.z, bA.w, bB.x, bB.y, bB.z, bB.w};
#pragma unroll
                for (int m = 0; m < 8; ++m)
#pragma unroll
                    for (int n = 0; n < 8; ++n)
                        acc[m][n] += am[m] * bn[n];
            }
            __syncthreads();
        }

        // upper tile write (rows a, cols b)
#pragma unroll
        for (int m = 0; m < 8; ++m) {
            const int a = a0 + ty * 8 + m;
            if (a >= NATOMS) continue;
            const int bAc = b0 + tx * 4;
            const int bBc = b0 + 64 + tx * 4;
            if (bAc < GSTRIDE) {
                *(float4*)&Gp[(size_t)a * GSTRIDE + bAc] =
                    make_float4(acc[m][0], acc[m][1], acc[m][2], acc[m][3]);
            }
            if (bBc < GSTRIDE) {
                *(float4*)&Gp[(size_t)a * GSTRIDE + bBc] =
                    make_float4(acc[m][4], acc[m][5], acc[m][6], acc[m][7]);
            }
        }
        // mirror write (rows b, cols a), register float4s; bx<by => a-range <1024
        if (bx != by) {
#pragma unroll
            for (int n = 0; n < 8; ++n) {
                const int colg = b0 + ((n < 4) ? (tx * 4 + n) : (64 + tx * 4 + (n - 4)));
                if (colg >= NATOMS) continue;
                const int a = a0 + ty * 8;
                *(float4*)&Gp[(size_t)colg * GSTRIDE + a] =
                    make_float4(acc[0][n], acc[1][n], acc[2][n], acc[3][n]);
                *(float4*)&Gp[(size_t)colg * GSTRIDE + a + 4] =
                    make_float4(acc[4][n], acc[5][n], acc[6][n], acc[7][n]);
            }
        }
    } else {
        // ================= projy role =================
        const int pw = blockIdx.y * 9 + blockIdx.x;
        if (pw >= 68) return;
        const int a0 = (pw % 17) * 64;
        const int b0 = (pw / 17) * 16;
        float* Ds = lds;            // [32][64]
        float* Ys = lds + 2048;     // [32][17]
        const int tx = tid & 15;
        const int ty = tid >> 4;
        const bool aIn = (a0 + 64) <= 1024;

        float acc[4] = {0.0f, 0.0f, 0.0f, 0.0f};

        for (int kc = 0; kc < 1024; kc += 32) {
            {
                const int r  = tid >> 4;
                const int c4 = (tid & 15) * 4;
#pragma unroll
                for (int rr = 0; rr < 2; ++rr) {
                    const int row = r + rr * 16;
                    const int l = kc + row;
                    if (aIn) {
                        *(float4*)&Ds[row * 64 + c4] = *(const float4*)&X0[(size_t)l * 1024 + a0 + c4];
                    } else {
#pragma unroll
                        for (int k = 0; k < 4; ++k) {
                            const int col = a0 + c4 + k;
                            Ds[row * 64 + c4 + k] = (col < 1024) ? X0[(size_t)l * 1024 + col]
                                                                 : (col == 1024 ? 1.0f : 0.0f);
                        }
                    }
                }
            }
            for (int e = tid; e < 512; e += 256) {
                const int l = e & 31, bb = e >> 5;
                Ys[l * 17 + bb] = y[(size_t)(b0 + bb) * 1024 + kc + l];
            }
            __syncthreads();
#pragma unroll 8
            for (int l = 0; l < 32; ++l) {
                const float yv = Ys[l * 17 + ty];
                float4 dv = *(const float4*)&Ds[l * 64 + tx * 4];
                acc[0] += yv * dv.x; acc[1] += yv * dv.y;
                acc[2] += yv * dv.z; acc[3] += yv * dv.w;
            }
            __syncthreads();
        }
        const int a = a0 + tx * 4;
        if (a < GSTRIDE) {
            *(float4*)&PY[(size_t)(b0 + ty) * GSTRIDE + a] =
                make_float4(acc[0], acc[1], acc[2], acc[3]);
        }
    }
}

// ---------------------------------------------------------------------------
// omp hybrid (R12 regs + colT border): one wg/batch, 512 threads (8 waves),
// ONE barrier/iter. Rows in REGISTERS rr0/rr1 (macro-stamped static indexing)
// for the j-loop; rows ALSO written transposed to colT[a*33+j] so the border
// b[m] = colT[sel*33+m] is a broadcast read (no owner 32-store hop, no bvec
// barrier). Intra-iter colT[.][i] write vs solve read race is benign: ainv
// row/col i is structurally zero until this iteration's rank-1 update.
// Staging loads issue after winner; vmcnt deferred past the j-loop.
// ---------------------------------------------------------------------------
template <int NS>
__global__ __launch_bounds__(512)
void omp_kernel(const float* __restrict__ Gp, const float* __restrict__ PY,
                int* __restrict__ idxOut, float* __restrict__ wOut) {
    __shared__ float colT[NATOMS * CSTRIDE];   // 135,300 B
    __shared__ float pyLds[1040];
    __shared__ float diagLds[1040];
    __shared__ float redV[2][8];
    __shared__ int   redI[2][8];

    const int b = blockIdx.x, tid = threadIdx.x;
    const int lane = tid & 63, wid = tid >> 6;

    float rr0[NNZ], rr1[NNZ];     // my two atoms of every staged row
    float ainv[32];
#pragma unroll
    for (int m = 0; m < 32; ++m) { ainv[m] = 0.f; rr0[m] = 0.f; rr1[m] = 0.f; }
    float wvr = 0.f, rhsr = 0.f;
    int   myIdx = 0;

    // ---- init: zero colT; load py; diag from the NS partial diagonals
    {
        for (int u = tid; u < NATOMS * CSTRIDE; u += 512) colT[u] = 0.f;
        const float* pyg = PY + (size_t)b * GSTRIDE;
        pyLds[tid] = pyg[tid];
        pyLds[tid + 512] = pyg[tid + 512];
        if (tid < 16) pyLds[1024 + tid] = pyg[1024 + tid];
        float d0 = 0.f, d1 = 0.f, d2 = 0.f;
#pragma unroll
        for (int z = 0; z < NS; ++z) {
            const float* gz = Gp + (size_t)z * GELEMS;
            d0 += gz[(size_t)tid * (GSTRIDE + 1)];
            d1 += gz[(size_t)(tid + 512) * (GSTRIDE + 1)];
            if (tid == 511) d2 += gz[(size_t)1024 * (GSTRIDE + 1)];
        }
        diagLds[tid] = d0;
        diagLds[tid + 512] = d1;
        if (tid == 511) diagLds[1024] = d2;
    }
    __syncthreads();

    float p0 = pyLds[tid], p1 = pyLds[tid + 512];
    float p2 = (tid == 511) ? pyLds[1024] : 0.f;

    // ---- prologue argmax on |py| -> parity 0
#define AM_STEP(ctrl) {                                                        \
        float ov = DPPF(wv_, ctrl);                                            \
        int   oi = __builtin_amdgcn_update_dpp(0, wi_, (ctrl), 0xF, 0xF, false);\
        if (ov > wv_ || (ov == wv_ && oi < wi_)) { wv_ = ov; wi_ = oi; } }
    {
        float best = fabsf(p0); int bidx = tid;
        { float v = fabsf(p1); if (v > best) { best = v; bidx = tid + 512; } }
        if (tid == 511) { float v = fabsf(p2); if (v > best) { best = v; bidx = 1024; } }
        float wv_ = best; int wi_ = bidx;
        AM_STEP(0x111) AM_STEP(0x112) AM_STEP(0x114) AM_STEP(0x118)
        AM_STEP(0x142) AM_STEP(0x143)
        wv_ = readlane_f(wv_, 63);
        wi_ = __builtin_amdgcn_readlane(wi_, 63);
        if (lane == 0) { redV[0][wid] = wv_; redI[0][wid] = wi_; }
    }
    __syncthreads();

    // ================= macro-stamped main loop (static register indexing) ====
#define OMP_ITER(I)                                                            \
    {                                                                          \
        const int par = (I) & 1;                                               \
        float bv_ = redV[par][0]; int sel = redI[par][0];                      \
        _Pragma("unroll")                                                      \
        for (int q = 1; q < 8; ++q) {                                          \
            if (redV[par][q] > bv_ ||                                          \
                (redV[par][q] == bv_ && redI[par][q] < sel)) {                 \
                bv_ = redV[par][q]; sel = redI[par][q];                        \
            }                                                                  \
        }                                                                      \
        const float pysel = pyLds[sel];                                        \
        float rA0=0.f,rA1=0.f,rA2=0.f,rA3=0.f;                                 \
        float rB0=0.f,rB1=0.f,rB2=0.f,rB3=0.f,rC=0.f;                          \
        if ((I) < NNZ - 1) {                                                   \
            const size_t ro = (size_t)sel * GSTRIDE;                           \
            { const float* g = Gp + ro; rA0 = g[tid]; rB0 = g[tid + 512]; }    \
            if (NS > 1) { const float* g = Gp + ro + (size_t)1 * GELEMS;       \
                          rA1 = g[tid]; rB1 = g[tid + 512]; }                  \
            if (NS > 2) { const float* g = Gp + ro + (size_t)2 * GELEMS;       \
                          rA2 = g[tid]; rB2 = g[tid + 512]; }                  \
            if (NS > 3) { const float* g = Gp + ro + (size_t)3 * GELEMS;       \
                          rA3 = g[tid]; rB3 = g[tid + 512]; }                  \
            if (tid == 511) {                                                  \
                _Pragma("unroll")                                              \
                for (int z = 0; z < NS; ++z)                                   \
                    rC += Gp[(size_t)z * GELEMS + ro + 1024];                  \
            }                                                                  \
        }                                                                      \
        const float* csel = &colT[sel * CSTRIDE];                              \
        const float bvl = (lane < 32) ? csel[lane] : 0.f;                      \
        float u0 = 0.f, u1 = 0.f;                                              \
        _Pragma("unroll")                                                      \
        for (int m = 0; m < 32; m += 2) {                                      \
            u0 = fmaf(ainv[m],     csel[m],     u0);                           \
            u1 = fmaf(ainv[m + 1], csel[m + 1], u1);                           \
        }                                                                      \
        const float uacc = u0 + u1;                                            \
        const float t = wave_sum64(bvl * uacc);                                \
        const float s = wave_sum64(rhsr * uacc);                               \
        const float dinv = 1.0f / (diagLds[sel] + REGL - t);                   \
        const float beta = dinv * (pysel - s);                                 \
        const float uvb = (lane == (I)) ? -1.0f : uacc;                        \
        _Pragma("unroll")                                                      \
        for (int m = 0; m < 32; ++m)                                           \
            ainv[m] = fmaf(uvb * dinv, readlane_f(uvb, m), ainv[m]);           \
        wvr  = (lane == (I)) ? beta  : fmaf(-uacc, beta, wvr);                 \
        rhsr = (lane == (I)) ? pysel : rhsr;                                   \
        if (tid == (I)) myIdx = sel;                                           \
        if ((I) < NNZ - 1) {                                                   \
            float z0 = 0.f, z1 = 0.f, z2 = 0.f;                                \
            _Pragma("unroll")                                                  \
            for (int j = 0; j < NNZ - 1; ++j) {                                \
                if (j < (I)) {                                                 \
                    const float uj = readlane_f(uvb, j);                       \
                    z0 = fmaf(uj, rr0[j], z0);                                 \
                    z1 = fmaf(uj, rr1[j], z1);                                 \
                    if (tid == 511) z2 = fmaf(uj, colT[1024 * CSTRIDE + j], z2); \
                }                                                              \
            }                                                                  \
            const float r0 = (rA0 + rA1) + (rA2 + rA3);                        \
            const float r1 = (rB0 + rB1) + (rB2 + rB3);                        \
            p0 = fmaf(beta, z0, p0); p0 = fmaf(-beta, r0, p0);                 \
            p1 = fmaf(beta, z1, p1); p1 = fmaf(-beta, r1, p1);                 \
            if (tid == 511) { p2 = fmaf(beta, z2, p2);                         \
                              p2 = fmaf(-beta, rC, p2); }                      \
            rr0[(I)] = r0; rr1[(I)] = r1;                                      \
            colT[tid * CSTRIDE + (I)] = r0;                                    \
            colT[(tid + 512) * CSTRIDE + (I)] = r1;                            \
            if (tid == 511) colT[1024 * CSTRIDE + (I)] = rC;                   \
            float best = fabsf(p0); int bidx = tid;                            \
            { float v = fabsf(p1); if (v > best) { best = v; bidx = tid + 512; } } \
            if (tid == 511) { float v = fabsf(p2);                             \
                              if (v > best) { best = v; bidx = 1024; } }       \
            float wv_ = best; int wi_ = bidx;                                  \
            AM_STEP(0x111) AM_STEP(0x112) AM_STEP(0x114) AM_STEP(0x118)       \
            AM_STEP(0x142) AM_STEP(0x143)                                      \
            wv_ = readlane_f(wv_, 63);                                         \
            wi_ = __builtin_amdgcn_readlane(wi_, 63);                          \
            if (lane == 0) { redV[par ^ 1][wid] = wv_;                         \
                             redI[par ^ 1][wid] = wi_; }                       \
            __syncthreads();                 /* the ONE barrier */             \
        }                                                                      \
    }

    OMP_ITER(0)  OMP_ITER(1)  OMP_ITER(2)  OMP_ITER(3)
    OMP_ITER(4)  OMP_ITER(5)  OMP_ITER(6)  OMP_ITER(7)
    OMP_ITER(8)  OMP_ITER(9)  OMP_ITER(10) OMP_ITER(11)
    OMP_ITER(12) OMP_ITER(13) OMP_ITER(14) OMP_ITER(15)
    OMP_ITER(16) OMP_ITER(17) OMP_ITER(18) OMP_ITER(19)
    OMP_ITER(20) OMP_ITER(21) OMP_ITER(22) OMP_ITER(23)
    OMP_ITER(24) OMP_ITER(25) OMP_ITER(26) OMP_ITER(27)
    OMP_ITER(28) OMP_ITER(29) OMP_ITER(30) OMP_ITER(31)
#undef OMP_ITER
#undef AM_STEP

    if (tid < NNZ) {
        idxOut[b * NNZ + tid] = myIdx;
        wOut[b * NNZ + tid] = wvr;
    }
}

// ---------------------------------------------------------------------------
// recon (sparse, R12 version): out[b][l] = sum_i X[b][l][widx_i]*wval_i + bias.
// Dup last-wins semantics preserved via dense scatter + gather-and-zero;
// atom 1024 (ones column) redirected into the bias. Reads only the 32
// selected columns of X (~128 MB of 64B lines vs 268 MB dense).
// ---------------------------------------------------------------------------
__global__ __launch_bounds__(256)
void recon_kernel(const float* __restrict__ X, const int* __restrict__ idxIn,
                  const float* __restrict__ wIn, float* __restrict__ out) {
    __shared__ float Wd[1025];
    __shared__ float wval[NNZ];
    __shared__ int   widx[NNZ];
    __shared__ float biasS;
    const int b = blockIdx.x >> 2, chunk = blockIdx.x & 3;
    const int tid = threadIdx.x;
    for (int u = tid; u < 1025; u += 256) Wd[u] = 0.0f;
    __syncthreads();
    if (tid == 0) {
#pragma unroll
        for (int i = 0; i < NNZ; ++i) Wd[idxIn[b * NNZ + i]] = wIn[b * NNZ + i];
        float bias = 0.0f;
#pragma unroll
        for (int i = 0; i < NNZ; ++i) {
            const int gi = idxIn[b * NNZ + i];
            const float v = Wd[gi];
            Wd[gi] = 0.0f;                       // dup i reads 0 second time
            const bool isOnes = (gi == 1024);
            if (isOnes) bias += v;
            widx[i] = isOnes ? 0 : gi;
            wval[i] = isOnes ? 0.0f : v;
        }
        biasS = bias;
    }
    __syncthreads();
    const int l = chunk * 256 + tid;
    const float* __restrict__ xr = X + (size_t)b * 1024 * 1024 + (size_t)l * 1024;
    float a0 = biasS, a1 = 0.f, a2 = 0.f, a3 = 0.f;
#pragma unroll
    for (int i = 0; i < NNZ; i += 4) {
        a0 = fmaf(xr[widx[i + 0]], wval[i + 0], a0);
        a1 = fmaf(xr[widx[i + 1]], wval[i + 1], a1);
        a2 = fmaf(xr[widx[i + 2]], wval[i + 2], a2);
        a3 = fmaf(xr[widx[i + 3]], wval[i + 3], a3);
    }
    out[(size_t)b * 1024 + l] = (a0 + a1) + (a2 + a3);
}

// ---------------------------------------------------------------------------
extern "C" void kernel_launch(void* const* d_in, const int* in_sizes, int n_in,
                              void* d_out, int out_size, void* d_ws, size_t ws_size,
                              hipStream_t stream) {
    const float* X = (const float*)d_in[0];
    const float* y = (const float*)d_in[1];
    float* out = (float*)d_out;
    float* ws = (float*)d_ws;

    const size_t fixed = (size_t)64 * GSTRIDE + NBATCH * NNZ * 2 + 64;
    const size_t need4 = ((size_t)GELEMS * 4 + fixed) * sizeof(float);
    const int nsplit = (ws_size >= need4) ? 4 : 1;
    const int kLen = 1024 / nsplit;

    float* Gp = ws;
    float* PY = ws + (size_t)GELEMS * nsplit;
    float* wOut = PY + (size_t)64 * GSTRIDE;
    int* idxOut = (int*)(wOut + NBATCH * NNZ);

    gramprojy_kernel<<<dim3(9, 9, nsplit + 1), 256, 0, stream>>>(X, y, Gp, PY, kLen, nsplit);
    if (nsplit == 4) omp_kernel<4><<<NBATCH, 512, 0, stream>>>(Gp, PY, idxOut, wOut);
    else             omp_kernel<1><<<NBATCH, 512, 0, stream>>>(Gp, PY, idxOut, wOut);
    recon_kernel<<<NBATCH * 4, 256, 0, stream>>>(X, idxOut, wOut, out);
}